// Round 1
// 670.931 us; speedup vs baseline: 1.0961x; 1.0961x over previous
//
#include <hip/hip_runtime.h>
#include <math.h>

// Problem constants
#define B_ 256
#define I_ 512
#define H_ 1024
#define M_ 128
#define A_ 2048
#define R_ 4
#define S_ 3
#define O_ 512
#define RS_ 512      // R*M
#define P_ 926       // R*(M+S+3) + 3*M+S+3
#define PW_OFF 536   // R*(M+S+3)
#define NP_ 1438     // 926 (Wint) ++ 512 (Wo_h) concatenated N
#define SK_ 4        // split-K factor for the two big GEMMs

typedef unsigned short ushort_t;
typedef __attribute__((ext_vector_type(8))) short bf16x8;
typedef __attribute__((ext_vector_type(4))) float f32x4;
typedef __attribute__((ext_vector_type(4))) unsigned short u16x4;

__device__ __forceinline__ float sigmoidf_(float x) { return 1.0f / (1.0f + expf(-x)); }
__device__ __forceinline__ float softplusf_(float x) {
    return (x > 20.0f) ? x : log1pf(expf(x));
}
// f32 -> bf16 round-to-nearest-even
__device__ __forceinline__ ushort_t f2bf(float f) {
    unsigned int u = __float_as_uint(f);
    u = (u + 0x7FFFu + ((u >> 16) & 1u)) >> 16;
    return (ushort_t)u;
}

// sum of SK_ split-K partials of the p/oh GEMM (+ b_int bias), col < 926
__device__ __forceinline__ float pval(const float* __restrict__ pp,
                                      const float* __restrict__ b_int,
                                      int b, int col) {
    size_t o = (size_t)b * NP_ + col;
    size_t st = (size_t)B_ * NP_;
    return b_int[col] + pp[o] + pp[o + st] + pp[o + 2 * st] + pp[o + 3 * st];
}

// ---------------- block reductions (256 threads = 4 waves) ----------------
__device__ __forceinline__ float block_sum_(float v, float* red) {
    #pragma unroll
    for (int off = 32; off; off >>= 1) v += __shfl_down(v, off, 64);
    __syncthreads();
    if ((threadIdx.x & 63) == 0) red[threadIdx.x >> 6] = v;
    __syncthreads();
    return red[0] + red[1] + red[2] + red[3];
}
__device__ __forceinline__ float block_max_(float v, float* red) {
    #pragma unroll
    for (int off = 32; off; off >>= 1) v = fmaxf(v, __shfl_down(v, off, 64));
    __syncthreads();
    if ((threadIdx.x & 63) == 0) red[threadIdx.x >> 6] = v;
    __syncthreads();
    return fmaxf(fmaxf(red[0], red[1]), fmaxf(red[2], red[3]));
}

// ---------------- fused setup: 5 weight transposes + input prep ------------
// transpose+convert one 32x32 tile: WT[n][koff+k] = bf16(W[k][n])
__device__ __forceinline__ void transpose_tile(
    const float* __restrict__ W, ushort_t* __restrict__ WT,
    int K, int N, int ostride, int koff, int bx, int by, float (*tile)[33])
{
    int k0 = by * 32, n0 = bx * 32;
    int tx = threadIdx.x & 31, ty = threadIdx.x >> 5;  // ty 0..7
    #pragma unroll
    for (int i = 0; i < 4; ++i) {
        int k = ty + i * 8;
        int n = n0 + tx;
        float v = (n < N) ? W[(size_t)(k0 + k) * N + n] : 0.0f;
        tile[tx][k] = v;   // tile[n_local][k_local]
    }
    __syncthreads();
    #pragma unroll
    for (int i = 0; i < 4; ++i) {
        int nl = ty + i * 8;
        int n = n0 + nl;
        if (n < N) WT[(size_t)n * ostride + koff + k0 + tx] = f2bf(tile[nl][tx]);
    }
}

// region sizes: Wx 4096 | Wh 4096 | Wint 928 | Wo_h 512 | Wout 256 | prep 2048
__global__ __launch_bounds__(256) void setup_kernel(
    const float* __restrict__ x, const float* __restrict__ rv,
    const float* __restrict__ hp,
    const float* __restrict__ Wx, const float* __restrict__ Wh,
    const float* __restrict__ Wint, const float* __restrict__ Wo_h,
    const float* __restrict__ Wout,
    ushort_t* __restrict__ xin, ushort_t* __restrict__ WxhT,
    ushort_t* __restrict__ WpT, ushort_t* __restrict__ WoutT)
{
    __shared__ float tile[32][33];
    int r = blockIdx.x;
    if (r < 4096) { transpose_tile(Wx, WxhT, 1024, 4096, 2048, 0,    r % 128, r / 128, tile); return; }
    r -= 4096;
    if (r < 4096) { transpose_tile(Wh, WxhT, 1024, 4096, 2048, 1024, r % 128, r / 128, tile); return; }
    r -= 4096;
    if (r < 928)  { transpose_tile(Wint, WpT, 1024, 926, 1024, 0,    r % 29,  r / 29,  tile); return; }
    r -= 928;
    if (r < 512)  { transpose_tile(Wo_h, WpT + (size_t)926 * 1024, 1024, 512, 1024, 0, r % 16, r / 16, tile); return; }
    r -= 512;
    if (r < 256)  { transpose_tile(Wout, WoutT, 512, 512, 512, 0,    r % 16,  r / 16,  tile); return; }
    r -= 256;
    // prep: xin_bf = bf16([x | read_vec_prev | h_prev]); r in [0, 2048)
    int idx = r * 256 + threadIdx.x;   // B*2048
    int b = idx >> 11, j = idx & 2047;
    float v;
    if (j < 512)       v = x[b * 512 + j];
    else if (j < 1024) v = rv[b * 512 + (j - 512)];
    else               v = hp[b * 1024 + (j - 1024)];
    xin[idx] = f2bf(v);
}

// ---------------- bf16 MFMA GEMM, split-K partial output -------------------
// A: [M][lda] bf16; BT: [N][ldb] bf16 (W^T). blockIdx.z = split-K slice kz;
// each slice covers K range [kz*Ks, (kz+1)*Ks) and writes its own partial
// Cpart[kz][M][N] (f32, no bias). Consumers sum the SK_ partials.
template<bool NALIGN>
__global__ __launch_bounds__(256) void gemm_bf16_k(
    const ushort_t* __restrict__ A, int lda,
    const ushort_t* __restrict__ BT, int ldb,
    float* __restrict__ Cpart,
    int N, int Ks)
{
    __shared__ ushort_t As[64][40];   // pad 32->40 (80B rows: 2-way alias = free)
    __shared__ ushort_t Bs[64][40];
    int tid = threadIdx.x;
    int bm0 = blockIdx.y * 64, bn0 = blockIdx.x * 64;
    int kbeg = blockIdx.z * Ks, kend = kbeg + Ks;
    int srow = tid >> 2;              // staging: 64 rows x 4 threads x 8 elems
    int scol = (tid & 3) << 3;
    int wv = tid >> 6, l = tid & 63;
    int wm = (wv & 1) * 32, wn = (wv >> 1) * 32;
    int lane16 = l & 15, quad = l >> 4;

    f32x4 z4 = {0.0f, 0.0f, 0.0f, 0.0f};
    f32x4 acc00 = z4, acc01 = z4, acc10 = z4, acc11 = z4;

    const ushort_t* ap = A + (size_t)(bm0 + srow) * lda + scol;
    bool bvalid = NALIGN || (bn0 + srow) < N;
    const ushort_t* bp = BT + (size_t)(bn0 + srow) * ldb + scol;
    float4 fz = {0.0f, 0.0f, 0.0f, 0.0f};

    for (int k0 = kbeg; k0 < kend; k0 += 32) {
        *(float4*)&As[srow][scol] = *(const float4*)(ap + k0);
        if (bvalid) *(float4*)&Bs[srow][scol] = *(const float4*)(bp + k0);
        else        *(float4*)&Bs[srow][scol] = fz;
        __syncthreads();
        bf16x8 a0 = *(const bf16x8*)&As[wm + lane16][quad * 8];
        bf16x8 a1 = *(const bf16x8*)&As[wm + 16 + lane16][quad * 8];
        bf16x8 b0 = *(const bf16x8*)&Bs[wn + lane16][quad * 8];
        bf16x8 b1 = *(const bf16x8*)&Bs[wn + 16 + lane16][quad * 8];
        acc00 = __builtin_amdgcn_mfma_f32_16x16x32_bf16(a0, b0, acc00, 0, 0, 0);
        acc01 = __builtin_amdgcn_mfma_f32_16x16x32_bf16(a0, b1, acc01, 0, 0, 0);
        acc10 = __builtin_amdgcn_mfma_f32_16x16x32_bf16(a1, b0, acc10, 0, 0, 0);
        acc11 = __builtin_amdgcn_mfma_f32_16x16x32_bf16(a1, b1, acc11, 0, 0, 0);
        __syncthreads();
    }

    float* C = Cpart + (size_t)blockIdx.z * gridDim.y * 64 * N;
    // D layout: col = lane&15, row = quad*4 + reg
    #pragma unroll
    for (int gi = 0; gi < 2; ++gi) {
        #pragma unroll
        for (int gj = 0; gj < 2; ++gj) {
            const f32x4& acc = gi == 0 ? (gj == 0 ? acc00 : acc01)
                                       : (gj == 0 ? acc10 : acc11);
            int col = bn0 + wn + gj * 16 + lane16;
            if (NALIGN || col < N) {
                #pragma unroll
                for (int r2 = 0; r2 < 4; ++r2) {
                    int row = bm0 + wm + gi * 16 + quad * 4 + r2;
                    C[(size_t)row * N + col] = acc[r2];
                }
            }
        }
    }
}

// ---------------- LSTM gates (float4, sums 4 z-partials + bias) ------------
__global__ __launch_bounds__(256) void gates_kernel(
    const float* __restrict__ zpart, const float* __restrict__ b_lstm,
    const float* __restrict__ c_prev, ushort_t* __restrict__ h)
{
    int g = blockIdx.x * 256 + threadIdx.x;   // B*H/4 = 65536
    int b = g >> 8, j = (g & 255) << 2;
    size_t st = (size_t)B_ * 4096;
    size_t zb = (size_t)b * 4096 + j;
    f32x4 zs[4];
    #pragma unroll
    for (int q = 0; q < 4; ++q) {
        size_t o = zb + q * 1024;
        f32x4 v = *(const f32x4*)(zpart + o);
        v += *(const f32x4*)(zpart + o + st);
        v += *(const f32x4*)(zpart + o + 2 * st);
        v += *(const f32x4*)(zpart + o + 3 * st);
        v += *(const f32x4*)(b_lstm + q * 1024 + j);
        zs[q] = v;
    }
    f32x4 cp = *(const f32x4*)(c_prev + (size_t)b * 1024 + j);
    u16x4 hv;
    #pragma unroll
    for (int e = 0; e < 4; ++e) {
        float c = sigmoidf_(zs[1][e]) * cp[e] + sigmoidf_(zs[0][e]) * tanhf(zs[2][e]);
        hv[e] = f2bf(sigmoidf_(zs[3][e]) * tanhf(c));
    }
    *(u16x4*)(h + (size_t)b * 1024 + j) = hv;
}

// ---------------- pass 1: raw dots (5 heads) + column norms ----------------
__global__ __launch_bounds__(256) void sim_kernel(
    const float* __restrict__ mem, const float* __restrict__ pohpart,
    const float* __restrict__ b_int,
    float* __restrict__ dots,   // [B,5,A]
    float* __restrict__ mn)     // [B,A]
{
    int b = blockIdx.y;
    int a = blockIdx.x * 256 + threadIdx.x;
    __shared__ float ks[5][M_];
    for (int idx = threadIdx.x; idx < 5 * M_; idx += 256) {
        int h = idx >> 7, m = idx & 127;
        int col = (h < 4) ? h * 134 + m : PW_OFF + m;
        ks[h][m] = pval(pohpart, b_int, b, col);
    }
    __syncthreads();
    const float* mb = mem + (size_t)b * M_ * A_ + a;
    float d0 = 0, d1 = 0, d2 = 0, d3 = 0, d4 = 0, nn = 0;
    #pragma unroll 8
    for (int m = 0; m < M_; ++m) {
        float v = mb[(size_t)m * A_];
        d0 += v * ks[0][m]; d1 += v * ks[1][m]; d2 += v * ks[2][m];
        d3 += v * ks[3][m]; d4 += v * ks[4][m];
        nn += v * v;
    }
    size_t base = (size_t)b * 5 * A_ + a;
    dots[base + 0 * A_] = d0; dots[base + 1 * A_] = d1; dots[base + 2 * A_] = d2;
    dots[base + 3 * A_] = d3; dots[base + 4 * A_] = d4;
    mn[(size_t)b * A_ + a] = sqrtf(nn);
}

// ---------------- addressing: softmax -> gate -> shift -> sharpen ----------
__global__ __launch_bounds__(256) void address_kernel(
    const float* __restrict__ pohpart, const float* __restrict__ b_int,
    const float* __restrict__ dots, const float* __restrict__ mn,
    const float* __restrict__ read_w_prev, const float* __restrict__ write_w_prev,
    float* __restrict__ w_read, float* __restrict__ w_write)
{
    int head = blockIdx.x;
    int b = blockIdx.y;
    int t = threadIdx.x;
    __shared__ float wg[A_];
    __shared__ float red[4];

    int pb = (head < 4) ? head * 134 : PW_OFF;
    float beta  = softplusf_(pval(pohpart, b_int, b, pb + 128));
    float g     = sigmoidf_(pval(pohpart, b_int, b, pb + 129));
    float gamma = 1.0f + softplusf_(pval(pohpart, b_int, b, pb + 130));
    float e0 = pval(pohpart, b_int, b, pb + 131);
    float e1 = pval(pohpart, b_int, b, pb + 132);
    float e2 = pval(pohpart, b_int, b, pb + 133);
    float smax = fmaxf(e0, fmaxf(e1, e2));
    float x0 = __expf(e0 - smax), x1 = __expf(e1 - smax), x2 = __expf(e2 - smax);
    float sden = x0 + x1 + x2;
    float s0 = x0 / sden, s1 = x1 / sden, s2 = x2 / sden;

    float kacc = 0.0f;
    if (t < M_) { float kv = pval(pohpart, b_int, b, pb + t); kacc = kv * kv; }
    float kn = sqrtf(block_sum_(kacc, red));

    const float* db = dots + ((size_t)b * 5 + head) * A_;
    const float* mb = mn + (size_t)b * A_;
    float logit[8];
    float lmax = -1e30f;
    #pragma unroll
    for (int i = 0; i < 8; ++i) {
        int a = t + 256 * i;
        float sim = db[a] / (kn * mb[a] + 1e-8f);
        logit[i] = beta * sim;
        lmax = fmaxf(lmax, logit[i]);
    }
    lmax = block_max_(lmax, red);
    float ex[8]; float lsum = 0.0f;
    #pragma unroll
    for (int i = 0; i < 8; ++i) { ex[i] = __expf(logit[i] - lmax); lsum += ex[i]; }
    lsum = block_sum_(lsum, red);
    float inv_lsum = 1.0f / lsum;

    const float* wprev = (head < 4) ? read_w_prev + ((size_t)b * 4 + head) * A_
                                    : write_w_prev + (size_t)b * A_;
    #pragma unroll
    for (int i = 0; i < 8; ++i) {
        int a = t + 256 * i;
        wg[a] = g * (ex[i] * inv_lsum) + (1.0f - g) * wprev[a];
    }
    __syncthreads();
    float wpow[8]; float psum = 0.0f;
    #pragma unroll
    for (int i = 0; i < 8; ++i) {
        int a = t + 256 * i;
        float ws = s0 * wg[(a + 1) & (A_ - 1)] + s1 * wg[a] + s2 * wg[(a + A_ - 1) & (A_ - 1)];
        float wp2 = __expf(gamma * __logf(ws + 1e-12f));   // (ws+eps)^gamma, ws+eps > 0
        wpow[i] = wp2; psum += wp2;
    }
    psum = block_sum_(psum, red);
    float inv = 1.0f / (psum + 1e-8f);
    float* wout = (head < 4) ? w_read + ((size_t)b * 4 + head) * A_
                             : w_write + (size_t)b * A_;
    #pragma unroll
    for (int i = 0; i < 8; ++i) wout[t + 256 * i] = wpow[i] * inv;
}

// ---------------- pass 2: memory update + read vectors (float4) ------------
// One block per (b,m). Each wave streams a 512-col quarter as float4s.
__global__ __launch_bounds__(256) void update_kernel(
    const float* __restrict__ mem, const float* __restrict__ pohpart,
    const float* __restrict__ b_int,
    const float* __restrict__ w_read, const float* __restrict__ w_write,
    float* __restrict__ mem_new,      // -> d_out + B*O
    ushort_t* __restrict__ read_vec)  // [B, R*M] bf16
{
    int bm = blockIdx.x;
    int b = bm >> 7, m = bm & 127;
    int t = threadIdx.x;
    int wv = t >> 6, l = t & 63;
    // erase col = PW_OFF+134+m = 670+m ; add col = PW_OFF+262+m = 798+m
    float er = sigmoidf_(pval(pohpart, b_int, b, 670 + m));
    float ad = pval(pohpart, b_int, b, 798 + m);
    const f32x4* m4  = (const f32x4*)(mem + ((size_t)b * M_ + m) * A_);
    const f32x4* ww4 = (const f32x4*)(w_write + (size_t)b * A_);
    const f32x4* wr4 = (const f32x4*)(w_read + (size_t)b * 4 * A_);
    f32x4* o4 = (f32x4*)(mem_new + ((size_t)b * M_ + m) * A_);
    float s[4] = {0, 0, 0, 0};
    #pragma unroll
    for (int j = 0; j < 2; ++j) {
        int a4 = wv * 128 + l + 64 * j;      // float4 index within the row
        f32x4 v = m4[a4], w = ww4[a4];
        f32x4 r0 = wr4[a4], r1 = wr4[512 + a4], r2 = wr4[1024 + a4], r3 = wr4[1536 + a4];
        f32x4 ov;
        #pragma unroll
        for (int c = 0; c < 4; ++c) {
            ov[c] = v[c] * (1.0f - er * w[c]) + ad * w[c];
            s[0] += v[c] * r0[c];
            s[1] += v[c] * r1[c];
            s[2] += v[c] * r2[c];
            s[3] += v[c] * r3[c];
        }
        o4[a4] = ov;
    }
    __shared__ float part[4][4];   // [wave][r]
    #pragma unroll
    for (int r = 0; r < 4; ++r) {
        float v = s[r];
        #pragma unroll
        for (int off = 32; off; off >>= 1) v += __shfl_down(v, off, 64);
        if (l == 0) part[wv][r] = v;
    }
    __syncthreads();
    if (t < 4) {
        float sum = part[0][t] + part[1][t] + part[2][t] + part[3][t];
        read_vec[(size_t)b * RS_ + t * M_ + m] = f2bf(sum);
    }
}

// ---------------- final GEMM: out = rv@Wout + b_out + (oh partials + bo_h) -
// M=256, N=512, K=512. oh lives in pohpart cols [926, 1438).
__global__ __launch_bounds__(256) void gemm_final_k(
    const ushort_t* __restrict__ A,    // rv_bf, lda=512
    const ushort_t* __restrict__ BT,   // WoutT, ldb=512
    const float* __restrict__ pohpart,
    const float* __restrict__ bo_h, const float* __restrict__ b_out,
    float* __restrict__ C)
{
    __shared__ ushort_t As[64][40];
    __shared__ ushort_t Bs[64][40];
    int tid = threadIdx.x;
    int bm0 = blockIdx.y * 64, bn0 = blockIdx.x * 64;
    int srow = tid >> 2, scol = (tid & 3) << 3;
    int wv = tid >> 6, l = tid & 63;
    int wm = (wv & 1) * 32, wn = (wv >> 1) * 32;
    int lane16 = l & 15, quad = l >> 4;

    f32x4 z4 = {0.0f, 0.0f, 0.0f, 0.0f};
    f32x4 acc00 = z4, acc01 = z4, acc10 = z4, acc11 = z4;
    const ushort_t* ap = A + (size_t)(bm0 + srow) * 512 + scol;
    const ushort_t* bp = BT + (size_t)(bn0 + srow) * 512 + scol;

    for (int k0 = 0; k0 < 512; k0 += 32) {
        *(float4*)&As[srow][scol] = *(const float4*)(ap + k0);
        *(float4*)&Bs[srow][scol] = *(const float4*)(bp + k0);
        __syncthreads();
        bf16x8 a0 = *(const bf16x8*)&As[wm + lane16][quad * 8];
        bf16x8 a1 = *(const bf16x8*)&As[wm + 16 + lane16][quad * 8];
        bf16x8 b0 = *(const bf16x8*)&Bs[wn + lane16][quad * 8];
        bf16x8 b1 = *(const bf16x8*)&Bs[wn + 16 + lane16][quad * 8];
        acc00 = __builtin_amdgcn_mfma_f32_16x16x32_bf16(a0, b0, acc00, 0, 0, 0);
        acc01 = __builtin_amdgcn_mfma_f32_16x16x32_bf16(a0, b1, acc01, 0, 0, 0);
        acc10 = __builtin_amdgcn_mfma_f32_16x16x32_bf16(a1, b0, acc10, 0, 0, 0);
        acc11 = __builtin_amdgcn_mfma_f32_16x16x32_bf16(a1, b1, acc11, 0, 0, 0);
        __syncthreads();
    }

    size_t st = (size_t)B_ * NP_;
    #pragma unroll
    for (int gi = 0; gi < 2; ++gi) {
        #pragma unroll
        for (int gj = 0; gj < 2; ++gj) {
            const f32x4& acc = gi == 0 ? (gj == 0 ? acc00 : acc01)
                                       : (gj == 0 ? acc10 : acc11);
            int col = bn0 + wn + gj * 16 + lane16;
            float badd = bo_h[col] + b_out[col];
            #pragma unroll
            for (int r2 = 0; r2 < 4; ++r2) {
                int row = bm0 + wm + gi * 16 + quad * 4 + r2;   // = batch index
                size_t o = (size_t)row * NP_ + 926 + col;
                float oh = pohpart[o] + pohpart[o + st] + pohpart[o + 2 * st] + pohpart[o + 3 * st];
                C[(size_t)row * 512 + col] = acc[r2] + badd + oh;
            }
        }
    }
}

extern "C" void kernel_launch(void* const* d_in, const int* in_sizes, int n_in,
                              void* d_out, int out_size, void* d_ws, size_t ws_size,
                              hipStream_t stream) {
    (void)in_sizes; (void)n_in; (void)out_size; (void)ws_size;
    const float* x            = (const float*)d_in[0];
    const float* h_prev       = (const float*)d_in[1];
    const float* c_prev       = (const float*)d_in[2];
    const float* read_w_prev  = (const float*)d_in[3];
    const float* write_w_prev = (const float*)d_in[4];
    const float* memory_prev  = (const float*)d_in[5];
    const float* read_vec_prev= (const float*)d_in[6];
    const float* Wx           = (const float*)d_in[7];
    const float* Wh           = (const float*)d_in[8];
    const float* b_lstm       = (const float*)d_in[9];
    const float* Wo_h         = (const float*)d_in[10];
    const float* bo_h         = (const float*)d_in[11];
    const float* Wint         = (const float*)d_in[12];
    const float* b_int        = (const float*)d_in[13];
    const float* Wout         = (const float*)d_in[14];
    const float* b_out        = (const float*)d_in[15];
    float* out = (float*)d_out;                  // [B*O] ++ [B*M*A]
    float* mem_new_out = out + (size_t)B_ * O_;

    char* wsp = (char*)d_ws;
    ushort_t* xin_bf = (ushort_t*)wsp; wsp += (size_t)B_ * 2048 * 2;          // 1 MB
    ushort_t* h_bf   = (ushort_t*)wsp; wsp += (size_t)B_ * H_ * 2;            // 0.5 MB
    ushort_t* rv_bf  = (ushort_t*)wsp; wsp += (size_t)B_ * RS_ * 2;           // 0.25 MB
    ushort_t* WxhT   = (ushort_t*)wsp; wsp += (size_t)4096 * 2048 * 2;        // 16 MB
    ushort_t* WpT    = (ushort_t*)wsp; wsp += (size_t)NP_ * 1024 * 2;         // 2.94 MB
    ushort_t* WoutT  = (ushort_t*)wsp; wsp += (size_t)512 * 512 * 2;          // 0.5 MB
    float* zpart     = (float*)wsp;    wsp += (size_t)SK_ * B_ * 4096 * 4;    // 16 MB
    float* pohpart   = (float*)wsp;    wsp += (size_t)SK_ * B_ * NP_ * 4;     // 5.9 MB
    float* dots      = (float*)wsp;    wsp += (size_t)B_ * 5 * A_ * 4;        // 10.5 MB
    float* mn        = (float*)wsp;    wsp += (size_t)B_ * A_ * 4;            // 2 MB
    float* w_read    = (float*)wsp;    wsp += (size_t)B_ * R_ * A_ * 4;       // 8 MB
    float* w_write   = (float*)wsp;    wsp += (size_t)B_ * A_ * 4;            // 2 MB

    // 1. setup: all weight transposes (bf16) + xin prep in one dispatch
    setup_kernel<<<dim3(4096 + 4096 + 928 + 512 + 256 + 2048), 256, 0, stream>>>(
        x, read_vec_prev, h_prev, Wx, Wh, Wint, Wo_h, Wout,
        xin_bf, WxhT, WpT, WoutT);
    // 2. z partials = xin @ [Wx;Wh]  (split-K=4: grid 1024 blocks = 4/CU)
    gemm_bf16_k<true><<<dim3(4096 / 64, B_ / 64, SK_), 256, 0, stream>>>(
        xin_bf, 2048, WxhT, 2048, zpart, 4096, 2048 / SK_);
    // 3. gates -> h (bf16); sums z partials + b_lstm
    gates_kernel<<<dim3(B_ * H_ / 1024), 256, 0, stream>>>(zpart, b_lstm, c_prev, h_bf);
    // 4. poh partials = h @ [Wint|Wo_h]  (N=1438, split-K=4: 368 blocks)
    gemm_bf16_k<false><<<dim3(23, B_ / 64, SK_), 256, 0, stream>>>(
        h_bf, 1024, WpT, 1024, pohpart, NP_, 1024 / SK_);
    // 5. dots + norms (first pass over memory)
    sim_kernel<<<dim3(A_ / 256, B_), 256, 0, stream>>>(memory_prev, pohpart, b_int, dots, mn);
    // 6. addressing for 4 read heads + 1 write head
    address_kernel<<<dim3(5, B_), 256, 0, stream>>>(
        pohpart, b_int, dots, mn, read_w_prev, write_w_prev, w_read, w_write);
    // 7. memory update + read vectors (second pass over memory)
    update_kernel<<<dim3(B_ * M_), 256, 0, stream>>>(
        memory_prev, pohpart, b_int, w_read, w_write, mem_new_out, rv_bf);
    // 8. final_output = (oh partials + bo_h) + rv @ Wout + b_out
    gemm_final_k<<<dim3(O_ / 64, B_ / 64), 256, 0, stream>>>(
        rv_bf, WoutT, pohpart, bo_h, b_out, out);
}

// Round 2
// 635.343 us; speedup vs baseline: 1.1575x; 1.0560x over previous
//
#include <hip/hip_runtime.h>
#include <math.h>

// Problem constants
#define B_ 256
#define I_ 512
#define H_ 1024
#define M_ 128
#define A_ 2048
#define R_ 4
#define S_ 3
#define O_ 512
#define RS_ 512      // R*M
#define P_ 926       // R*(M+S+3) + 3*M+S+3
#define PW_OFF 536   // R*(M+S+3)
#define NP_ 1438     // 926 (Wint) ++ 512 (Wo_h) concatenated N
#define SK_ 4        // split-K factor for the two big GEMMs

typedef unsigned short ushort_t;
typedef __attribute__((ext_vector_type(8))) short bf16x8;
typedef __attribute__((ext_vector_type(4))) float f32x4;
typedef __attribute__((ext_vector_type(4))) unsigned short u16x4;

__device__ __forceinline__ float sigmoidf_(float x) { return 1.0f / (1.0f + expf(-x)); }
__device__ __forceinline__ float softplusf_(float x) {
    return (x > 20.0f) ? x : log1pf(expf(x));
}
// f32 -> bf16 round-to-nearest-even
__device__ __forceinline__ ushort_t f2bf(float f) {
    unsigned int u = __float_as_uint(f);
    u = (u + 0x7FFFu + ((u >> 16) & 1u)) >> 16;
    return (ushort_t)u;
}

// sum of SK_ split-K partials of the p/oh GEMM (+ b_int bias), col < 926
__device__ __forceinline__ float pval(const float* __restrict__ pp,
                                      const float* __restrict__ b_int,
                                      int b, int col) {
    size_t o = (size_t)b * NP_ + col;
    size_t st = (size_t)B_ * NP_;
    return b_int[col] + pp[o] + pp[o + st] + pp[o + 2 * st] + pp[o + 3 * st];
}

// ---------------- block reductions (256 threads = 4 waves) ----------------
__device__ __forceinline__ float block_sum_(float v, float* red) {
    #pragma unroll
    for (int off = 32; off; off >>= 1) v += __shfl_down(v, off, 64);
    __syncthreads();
    if ((threadIdx.x & 63) == 0) red[threadIdx.x >> 6] = v;
    __syncthreads();
    return red[0] + red[1] + red[2] + red[3];
}
__device__ __forceinline__ float block_max_(float v, float* red) {
    #pragma unroll
    for (int off = 32; off; off >>= 1) v = fmaxf(v, __shfl_down(v, off, 64));
    __syncthreads();
    if ((threadIdx.x & 63) == 0) red[threadIdx.x >> 6] = v;
    __syncthreads();
    return fmaxf(fmaxf(red[0], red[1]), fmaxf(red[2], red[3]));
}

// ---------------- fused setup: 5 weight transposes + input prep ------------
// transpose+convert one 32x32 tile: WT[n][koff+k] = bf16(W[k][n])
__device__ __forceinline__ void transpose_tile(
    const float* __restrict__ W, ushort_t* __restrict__ WT,
    int K, int N, int ostride, int koff, int bx, int by, float (*tile)[33])
{
    int k0 = by * 32, n0 = bx * 32;
    int tx = threadIdx.x & 31, ty = threadIdx.x >> 5;  // ty 0..7
    #pragma unroll
    for (int i = 0; i < 4; ++i) {
        int k = ty + i * 8;
        int n = n0 + tx;
        float v = (n < N) ? W[(size_t)(k0 + k) * N + n] : 0.0f;
        tile[tx][k] = v;   // tile[n_local][k_local]
    }
    __syncthreads();
    #pragma unroll
    for (int i = 0; i < 4; ++i) {
        int nl = ty + i * 8;
        int n = n0 + nl;
        if (n < N) WT[(size_t)n * ostride + koff + k0 + tx] = f2bf(tile[nl][tx]);
    }
}

// region sizes: Wx 4096 | Wh 4096 | Wint 928 | Wo_h 512 | Wout 256 | prep 2048
__global__ __launch_bounds__(256) void setup_kernel(
    const float* __restrict__ x, const float* __restrict__ rv,
    const float* __restrict__ hp,
    const float* __restrict__ Wx, const float* __restrict__ Wh,
    const float* __restrict__ Wint, const float* __restrict__ Wo_h,
    const float* __restrict__ Wout,
    ushort_t* __restrict__ xin, ushort_t* __restrict__ WxhT,
    ushort_t* __restrict__ WpT, ushort_t* __restrict__ WoutT)
{
    __shared__ float tile[32][33];
    int r = blockIdx.x;
    if (r < 4096) { transpose_tile(Wx, WxhT, 1024, 4096, 2048, 0,    r % 128, r / 128, tile); return; }
    r -= 4096;
    if (r < 4096) { transpose_tile(Wh, WxhT, 1024, 4096, 2048, 1024, r % 128, r / 128, tile); return; }
    r -= 4096;
    if (r < 928)  { transpose_tile(Wint, WpT, 1024, 926, 1024, 0,    r % 29,  r / 29,  tile); return; }
    r -= 928;
    if (r < 512)  { transpose_tile(Wo_h, WpT + (size_t)926 * 1024, 1024, 512, 1024, 0, r % 16, r / 16, tile); return; }
    r -= 512;
    if (r < 256)  { transpose_tile(Wout, WoutT, 512, 512, 512, 0,    r % 16,  r / 16,  tile); return; }
    r -= 256;
    // prep: xin_bf = bf16([x | read_vec_prev | h_prev]); r in [0, 2048)
    int idx = r * 256 + threadIdx.x;   // B*2048
    int b = idx >> 11, j = idx & 2047;
    float v;
    if (j < 512)       v = x[b * 512 + j];
    else if (j < 1024) v = rv[b * 512 + (j - 512)];
    else               v = hp[b * 1024 + (j - 1024)];
    xin[idx] = f2bf(v);
}

// ---------------- bf16 MFMA GEMM, split-K partial output -------------------
// A: [M][lda] bf16; BT: [N][ldb] bf16 (W^T). blockIdx.z = split-K slice kz;
// each slice covers K range [kz*Ks, (kz+1)*Ks) and writes its own partial
// Cpart[kz][M][N] (f32, no bias). Consumers sum the SK_ partials.
template<bool NALIGN>
__global__ __launch_bounds__(256) void gemm_bf16_k(
    const ushort_t* __restrict__ A, int lda,
    const ushort_t* __restrict__ BT, int ldb,
    float* __restrict__ Cpart,
    int N, int Ks)
{
    __shared__ ushort_t As[64][40];   // pad 32->40 (80B rows: 2-way bank alias = free)
    __shared__ ushort_t Bs[64][40];
    int tid = threadIdx.x;
    int bm0 = blockIdx.y * 64, bn0 = blockIdx.x * 64;
    int kbeg = blockIdx.z * Ks, kend = kbeg + Ks;
    int srow = tid >> 2;              // staging: 64 rows x 4 threads x 8 elems
    int scol = (tid & 3) << 3;
    int wv = tid >> 6, l = tid & 63;
    int wm = (wv & 1) * 32, wn = (wv >> 1) * 32;
    int lane16 = l & 15, quad = l >> 4;

    f32x4 z4 = {0.0f, 0.0f, 0.0f, 0.0f};
    f32x4 acc00 = z4, acc01 = z4, acc10 = z4, acc11 = z4;

    const ushort_t* ap = A + (size_t)(bm0 + srow) * lda + scol;
    bool bvalid = NALIGN || (bn0 + srow) < N;
    const ushort_t* bp = BT + (size_t)(bn0 + srow) * ldb + scol;
    float4 fz = {0.0f, 0.0f, 0.0f, 0.0f};

    for (int k0 = kbeg; k0 < kend; k0 += 32) {
        *(float4*)&As[srow][scol] = *(const float4*)(ap + k0);
        if (bvalid) *(float4*)&Bs[srow][scol] = *(const float4*)(bp + k0);
        else        *(float4*)&Bs[srow][scol] = fz;
        __syncthreads();
        bf16x8 a0 = *(const bf16x8*)&As[wm + lane16][quad * 8];
        bf16x8 a1 = *(const bf16x8*)&As[wm + 16 + lane16][quad * 8];
        bf16x8 b0 = *(const bf16x8*)&Bs[wn + lane16][quad * 8];
        bf16x8 b1 = *(const bf16x8*)&Bs[wn + 16 + lane16][quad * 8];
        acc00 = __builtin_amdgcn_mfma_f32_16x16x32_bf16(a0, b0, acc00, 0, 0, 0);
        acc01 = __builtin_amdgcn_mfma_f32_16x16x32_bf16(a0, b1, acc01, 0, 0, 0);
        acc10 = __builtin_amdgcn_mfma_f32_16x16x32_bf16(a1, b0, acc10, 0, 0, 0);
        acc11 = __builtin_amdgcn_mfma_f32_16x16x32_bf16(a1, b1, acc11, 0, 0, 0);
        __syncthreads();
    }

    float* C = Cpart + (size_t)blockIdx.z * gridDim.y * 64 * N;
    // D layout: col = lane&15, row = quad*4 + reg
    #pragma unroll
    for (int gi = 0; gi < 2; ++gi) {
        #pragma unroll
        for (int gj = 0; gj < 2; ++gj) {
            const f32x4& acc = gi == 0 ? (gj == 0 ? acc00 : acc01)
                                       : (gj == 0 ? acc10 : acc11);
            int col = bn0 + wn + gj * 16 + lane16;
            if (NALIGN || col < N) {
                #pragma unroll
                for (int r2 = 0; r2 < 4; ++r2) {
                    int row = bm0 + wm + gi * 16 + quad * 4 + r2;
                    C[(size_t)row * N + col] = acc[r2];
                }
            }
        }
    }
}

// ---------------- LSTM gates (float4, sums 4 z-partials + bias) ------------
__global__ __launch_bounds__(256) void gates_kernel(
    const float* __restrict__ zpart, const float* __restrict__ b_lstm,
    const float* __restrict__ c_prev, ushort_t* __restrict__ h)
{
    int g = blockIdx.x * 256 + threadIdx.x;   // B*H/4 = 65536
    int b = g >> 8, j = (g & 255) << 2;
    size_t st = (size_t)B_ * 4096;
    size_t zb = (size_t)b * 4096 + j;
    f32x4 zs[4];
    #pragma unroll
    for (int q = 0; q < 4; ++q) {
        size_t o = zb + q * 1024;
        f32x4 v = *(const f32x4*)(zpart + o);
        v += *(const f32x4*)(zpart + o + st);
        v += *(const f32x4*)(zpart + o + 2 * st);
        v += *(const f32x4*)(zpart + o + 3 * st);
        v += *(const f32x4*)(b_lstm + q * 1024 + j);
        zs[q] = v;
    }
    f32x4 cp = *(const f32x4*)(c_prev + (size_t)b * 1024 + j);
    u16x4 hv;
    #pragma unroll
    for (int e = 0; e < 4; ++e) {
        float c = sigmoidf_(zs[1][e]) * cp[e] + sigmoidf_(zs[0][e]) * tanhf(zs[2][e]);
        hv[e] = f2bf(sigmoidf_(zs[3][e]) * tanhf(c));
    }
    *(u16x4*)(h + (size_t)b * 1024 + j) = hv;
}

// ---------------- pass 1: raw dots (5 heads) + column norms ----------------
// f32x4: each thread owns 4 consecutive a's. grid (A/1024, B).
__global__ __launch_bounds__(256) void sim_kernel(
    const float* __restrict__ mem, const float* __restrict__ pohpart,
    const float* __restrict__ b_int,
    float* __restrict__ dots,   // [B,5,A]
    float* __restrict__ mn)     // [B,A]
{
    int b = blockIdx.y;
    int a = (blockIdx.x * 256 + threadIdx.x) * 4;
    __shared__ float ks[5][M_];
    for (int idx = threadIdx.x; idx < 5 * M_; idx += 256) {
        int h = idx >> 7, m = idx & 127;
        int col = (h < 4) ? h * 134 + m : PW_OFF + m;
        ks[h][m] = pval(pohpart, b_int, b, col);
    }
    __syncthreads();
    const float* mb = mem + (size_t)b * M_ * A_ + a;
    f32x4 z = {0.0f, 0.0f, 0.0f, 0.0f};
    f32x4 d0 = z, d1 = z, d2 = z, d3 = z, d4 = z, nn = z;
    #pragma unroll 2
    for (int m = 0; m < M_; m += 4) {
        f32x4 vv[4];
        #pragma unroll
        for (int mm = 0; mm < 4; ++mm)
            vv[mm] = *(const f32x4*)(mb + (size_t)(m + mm) * A_);
        f32x4 k0 = *(const f32x4*)&ks[0][m];
        f32x4 k1 = *(const f32x4*)&ks[1][m];
        f32x4 k2 = *(const f32x4*)&ks[2][m];
        f32x4 k3 = *(const f32x4*)&ks[3][m];
        f32x4 k4 = *(const f32x4*)&ks[4][m];
        #pragma unroll
        for (int mm = 0; mm < 4; ++mm) {
            #pragma unroll
            for (int c = 0; c < 4; ++c) {
                float v = vv[mm][c];
                d0[c] += v * k0[mm];
                d1[c] += v * k1[mm];
                d2[c] += v * k2[mm];
                d3[c] += v * k3[mm];
                d4[c] += v * k4[mm];
                nn[c] += v * v;
            }
        }
    }
    size_t base = (size_t)b * 5 * A_ + a;
    *(f32x4*)(dots + base + 0 * A_) = d0;
    *(f32x4*)(dots + base + 1 * A_) = d1;
    *(f32x4*)(dots + base + 2 * A_) = d2;
    *(f32x4*)(dots + base + 3 * A_) = d3;
    *(f32x4*)(dots + base + 4 * A_) = d4;
    f32x4 rt;
    #pragma unroll
    for (int c = 0; c < 4; ++c) rt[c] = sqrtf(nn[c]);
    *(f32x4*)(mn + (size_t)b * A_ + a) = rt;
}

// ---------------- addressing: softmax -> gate -> shift -> sharpen ----------
__global__ __launch_bounds__(256) void address_kernel(
    const float* __restrict__ pohpart, const float* __restrict__ b_int,
    const float* __restrict__ dots, const float* __restrict__ mn,
    const float* __restrict__ read_w_prev, const float* __restrict__ write_w_prev,
    float* __restrict__ w_read, float* __restrict__ w_write)
{
    int head = blockIdx.x;
    int b = blockIdx.y;
    int t = threadIdx.x;
    __shared__ float wg[A_];
    __shared__ float red[4];

    int pb = (head < 4) ? head * 134 : PW_OFF;
    float beta  = softplusf_(pval(pohpart, b_int, b, pb + 128));
    float g     = sigmoidf_(pval(pohpart, b_int, b, pb + 129));
    float gamma = 1.0f + softplusf_(pval(pohpart, b_int, b, pb + 130));
    float e0 = pval(pohpart, b_int, b, pb + 131);
    float e1 = pval(pohpart, b_int, b, pb + 132);
    float e2 = pval(pohpart, b_int, b, pb + 133);
    float smax = fmaxf(e0, fmaxf(e1, e2));
    float x0 = __expf(e0 - smax), x1 = __expf(e1 - smax), x2 = __expf(e2 - smax);
    float sden = x0 + x1 + x2;
    float s0 = x0 / sden, s1 = x1 / sden, s2 = x2 / sden;

    float kacc = 0.0f;
    if (t < M_) { float kv = pval(pohpart, b_int, b, pb + t); kacc = kv * kv; }
    float kn = sqrtf(block_sum_(kacc, red));

    const float* db = dots + ((size_t)b * 5 + head) * A_;
    const float* mb = mn + (size_t)b * A_;
    // two f32x4 chunks: a = 4t .. 4t+3 and 1024+4t .. 1024+4t+3
    f32x4 dA = *(const f32x4*)(db + 4 * t);
    f32x4 dB = *(const f32x4*)(db + 1024 + 4 * t);
    f32x4 mA = *(const f32x4*)(mb + 4 * t);
    f32x4 mB = *(const f32x4*)(mb + 1024 + 4 * t);
    f32x4 lA, lB;
    float lmax = -1e30f;
    #pragma unroll
    for (int c = 0; c < 4; ++c) {
        lA[c] = beta * dA[c] / (kn * mA[c] + 1e-8f);
        lB[c] = beta * dB[c] / (kn * mB[c] + 1e-8f);
        lmax = fmaxf(lmax, fmaxf(lA[c], lB[c]));
    }
    lmax = block_max_(lmax, red);
    f32x4 eA, eB;
    float lsum = 0.0f;
    #pragma unroll
    for (int c = 0; c < 4; ++c) {
        eA[c] = __expf(lA[c] - lmax);
        eB[c] = __expf(lB[c] - lmax);
        lsum += eA[c] + eB[c];
    }
    lsum = block_sum_(lsum, red);
    float inv_lsum = 1.0f / lsum;

    const float* wprev = (head < 4) ? read_w_prev + ((size_t)b * 4 + head) * A_
                                    : write_w_prev + (size_t)b * A_;
    f32x4 pA = *(const f32x4*)(wprev + 4 * t);
    f32x4 pB = *(const f32x4*)(wprev + 1024 + 4 * t);
    f32x4 gA, gB;
    #pragma unroll
    for (int c = 0; c < 4; ++c) {
        gA[c] = g * (eA[c] * inv_lsum) + (1.0f - g) * pA[c];
        gB[c] = g * (eB[c] * inv_lsum) + (1.0f - g) * pB[c];
    }
    *(f32x4*)&wg[4 * t] = gA;
    *(f32x4*)&wg[1024 + 4 * t] = gB;
    __syncthreads();
    f32x4 wA, wB;
    float psum = 0.0f;
    #pragma unroll
    for (int c = 0; c < 4; ++c) {
        int a = 4 * t + c;
        float ws = s0 * wg[(a + 1) & (A_ - 1)] + s1 * wg[a] + s2 * wg[(a + A_ - 1) & (A_ - 1)];
        wA[c] = __expf(gamma * __logf(ws + 1e-12f));
        a = 1024 + 4 * t + c;
        ws = s0 * wg[(a + 1) & (A_ - 1)] + s1 * wg[a] + s2 * wg[(a + A_ - 1) & (A_ - 1)];
        wB[c] = __expf(gamma * __logf(ws + 1e-12f));
        psum += wA[c] + wB[c];
    }
    psum = block_sum_(psum, red);
    float inv = 1.0f / (psum + 1e-8f);
    #pragma unroll
    for (int c = 0; c < 4; ++c) { wA[c] *= inv; wB[c] *= inv; }
    float* wout = (head < 4) ? w_read + ((size_t)b * 4 + head) * A_
                             : w_write + (size_t)b * A_;
    *(f32x4*)(wout + 4 * t) = wA;
    *(f32x4*)(wout + 1024 + 4 * t) = wB;
}

// ---------------- pass 2: memory update + read vectors ---------------------
// Block = (b, column-half, 8 m-rows). w rows register-cached across the 8 rows
// (8x less L2 w-traffic than one-block-per-(b,m)). rv written as 2 f32
// column-half partials; final GEMM sums them during A-staging.
__global__ __launch_bounds__(256) void update_kernel(
    const float* __restrict__ mem, const float* __restrict__ pohpart,
    const float* __restrict__ b_int,
    const float* __restrict__ w_read, const float* __restrict__ w_write,
    float* __restrict__ mem_new,      // -> d_out + B*O
    float* __restrict__ rv_part)      // [2][B][RS] f32
{
    int blk = blockIdx.x;             // B * 2 * 16
    int b = blk >> 5;
    int half = (blk >> 4) & 1;
    int m0 = (blk & 15) << 3;
    int t = threadIdx.x;
    int wv = t >> 6, l = t & 63;
    __shared__ float ser[8], sad[8];
    __shared__ float spart[4][8][4];
    if (t < 8)       ser[t] = sigmoidf_(pval(pohpart, b_int, b, 670 + m0 + t));
    else if (t < 16) sad[t - 8] = pval(pohpart, b_int, b, 798 + m0 + (t - 8));

    int col = half * 1024 + t * 4;
    const float* wrb = w_read + (size_t)b * 4 * A_ + col;
    f32x4 ww  = *(const f32x4*)(w_write + (size_t)b * A_ + col);
    f32x4 wr0 = *(const f32x4*)(wrb);
    f32x4 wr1 = *(const f32x4*)(wrb + A_);
    f32x4 wr2 = *(const f32x4*)(wrb + 2 * A_);
    f32x4 wr3 = *(const f32x4*)(wrb + 3 * A_);
    __syncthreads();

    float acc[8][4];
    #pragma unroll
    for (int mi = 0; mi < 8; ++mi)
        acc[mi][0] = acc[mi][1] = acc[mi][2] = acc[mi][3] = 0.0f;

    const float* mrow = mem + ((size_t)b * M_ + m0) * A_ + col;
    float* orow = mem_new + ((size_t)b * M_ + m0) * A_ + col;
    #pragma unroll
    for (int mi = 0; mi < 8; ++mi) {
        f32x4 v = *(const f32x4*)(mrow + (size_t)mi * A_);
        float er = ser[mi], ad = sad[mi];
        f32x4 ov;
        #pragma unroll
        for (int c = 0; c < 4; ++c) {
            ov[c] = v[c] * (1.0f - er * ww[c]) + ad * ww[c];
            acc[mi][0] += v[c] * wr0[c];
            acc[mi][1] += v[c] * wr1[c];
            acc[mi][2] += v[c] * wr2[c];
            acc[mi][3] += v[c] * wr3[c];
        }
        *(f32x4*)(orow + (size_t)mi * A_) = ov;
    }

    #pragma unroll
    for (int mi = 0; mi < 8; ++mi) {
        #pragma unroll
        for (int h = 0; h < 4; ++h) {
            float v = acc[mi][h];
            #pragma unroll
            for (int off = 32; off; off >>= 1) v += __shfl_down(v, off, 64);
            if (l == 0) spart[wv][mi][h] = v;
        }
    }
    __syncthreads();
    if (t < 32) {
        int mi = t >> 2, h = t & 3;
        float s = spart[0][mi][h] + spart[1][mi][h] + spart[2][mi][h] + spart[3][mi][h];
        rv_part[((size_t)half * B_ + b) * RS_ + h * M_ + m0 + mi] = s;
    }
}

// ---------------- final GEMM: out = rv@Wout + b_out + (oh partials + bo_h) -
// M=256, N=512, K=512. A staged by summing the 2 rv_part halves + f32->bf16.
// oh lives in pohpart cols [926, 1438).
__global__ __launch_bounds__(256) void gemm_final_k(
    const float* __restrict__ rv_part, // [2][B][RS] f32
    const ushort_t* __restrict__ BT,   // WoutT, ldb=512
    const float* __restrict__ pohpart,
    const float* __restrict__ bo_h, const float* __restrict__ b_out,
    float* __restrict__ C)
{
    __shared__ ushort_t As[64][40];
    __shared__ ushort_t Bs[64][40];
    int tid = threadIdx.x;
    int bm0 = blockIdx.y * 64, bn0 = blockIdx.x * 64;
    int srow = tid >> 2, scol = (tid & 3) << 3;
    int wv = tid >> 6, l = tid & 63;
    int wm = (wv & 1) * 32, wn = (wv >> 1) * 32;
    int lane16 = l & 15, quad = l >> 4;

    f32x4 z4 = {0.0f, 0.0f, 0.0f, 0.0f};
    f32x4 acc00 = z4, acc01 = z4, acc10 = z4, acc11 = z4;
    const float* rp0 = rv_part + (size_t)(bm0 + srow) * RS_ + scol;
    const float* rp1 = rp0 + (size_t)B_ * RS_;
    const ushort_t* bp = BT + (size_t)(bn0 + srow) * 512 + scol;

    for (int k0 = 0; k0 < 512; k0 += 32) {
        f32x4 u0 = *(const f32x4*)(rp0 + k0) + *(const f32x4*)(rp1 + k0);
        f32x4 u1 = *(const f32x4*)(rp0 + k0 + 4) + *(const f32x4*)(rp1 + k0 + 4);
        u16x4 w0, w1;
        #pragma unroll
        for (int c = 0; c < 4; ++c) { w0[c] = f2bf(u0[c]); w1[c] = f2bf(u1[c]); }
        *(u16x4*)&As[srow][scol] = w0;
        *(u16x4*)&As[srow][scol + 4] = w1;
        *(float4*)&Bs[srow][scol] = *(const float4*)(bp + k0);
        __syncthreads();
        bf16x8 a0 = *(const bf16x8*)&As[wm + lane16][quad * 8];
        bf16x8 a1 = *(const bf16x8*)&As[wm + 16 + lane16][quad * 8];
        bf16x8 b0 = *(const bf16x8*)&Bs[wn + lane16][quad * 8];
        bf16x8 b1 = *(const bf16x8*)&Bs[wn + 16 + lane16][quad * 8];
        acc00 = __builtin_amdgcn_mfma_f32_16x16x32_bf16(a0, b0, acc00, 0, 0, 0);
        acc01 = __builtin_amdgcn_mfma_f32_16x16x32_bf16(a0, b1, acc01, 0, 0, 0);
        acc10 = __builtin_amdgcn_mfma_f32_16x16x32_bf16(a1, b0, acc10, 0, 0, 0);
        acc11 = __builtin_amdgcn_mfma_f32_16x16x32_bf16(a1, b1, acc11, 0, 0, 0);
        __syncthreads();
    }

    size_t st = (size_t)B_ * NP_;
    #pragma unroll
    for (int gi = 0; gi < 2; ++gi) {
        #pragma unroll
        for (int gj = 0; gj < 2; ++gj) {
            const f32x4& acc = gi == 0 ? (gj == 0 ? acc00 : acc01)
                                       : (gj == 0 ? acc10 : acc11);
            int col = bn0 + wn + gj * 16 + lane16;
            float badd = bo_h[col] + b_out[col];
            #pragma unroll
            for (int r2 = 0; r2 < 4; ++r2) {
                int row = bm0 + wm + gi * 16 + quad * 4 + r2;   // = batch index
                size_t o = (size_t)row * NP_ + 926 + col;
                float oh = pohpart[o] + pohpart[o + st] + pohpart[o + 2 * st] + pohpart[o + 3 * st];
                C[(size_t)row * 512 + col] = acc[r2] + badd + oh;
            }
        }
    }
}

extern "C" void kernel_launch(void* const* d_in, const int* in_sizes, int n_in,
                              void* d_out, int out_size, void* d_ws, size_t ws_size,
                              hipStream_t stream) {
    (void)in_sizes; (void)n_in; (void)out_size; (void)ws_size;
    const float* x            = (const float*)d_in[0];
    const float* h_prev       = (const float*)d_in[1];
    const float* c_prev       = (const float*)d_in[2];
    const float* read_w_prev  = (const float*)d_in[3];
    const float* write_w_prev = (const float*)d_in[4];
    const float* memory_prev  = (const float*)d_in[5];
    const float* read_vec_prev= (const float*)d_in[6];
    const float* Wx           = (const float*)d_in[7];
    const float* Wh           = (const float*)d_in[8];
    const float* b_lstm       = (const float*)d_in[9];
    const float* Wo_h         = (const float*)d_in[10];
    const float* bo_h         = (const float*)d_in[11];
    const float* Wint         = (const float*)d_in[12];
    const float* b_int        = (const float*)d_in[13];
    const float* Wout         = (const float*)d_in[14];
    const float* b_out        = (const float*)d_in[15];
    float* out = (float*)d_out;                  // [B*O] ++ [B*M*A]
    float* mem_new_out = out + (size_t)B_ * O_;

    char* wsp = (char*)d_ws;
    ushort_t* xin_bf = (ushort_t*)wsp; wsp += (size_t)B_ * 2048 * 2;          // 1 MB
    ushort_t* h_bf   = (ushort_t*)wsp; wsp += (size_t)B_ * H_ * 2;            // 0.5 MB
    ushort_t* WxhT   = (ushort_t*)wsp; wsp += (size_t)4096 * 2048 * 2;        // 16 MB
    ushort_t* WpT    = (ushort_t*)wsp; wsp += (size_t)NP_ * 1024 * 2;         // 2.94 MB
    ushort_t* WoutT  = (ushort_t*)wsp; wsp += (size_t)512 * 512 * 2;          // 0.5 MB
    float* zpart     = (float*)wsp;    wsp += (size_t)SK_ * B_ * 4096 * 4;    // 16 MB
    float* pohpart   = (float*)wsp;    wsp += (size_t)SK_ * B_ * NP_ * 4;     // 5.9 MB
    float* dots      = (float*)wsp;    wsp += (size_t)B_ * 5 * A_ * 4;        // 10.5 MB
    float* mn        = (float*)wsp;    wsp += (size_t)B_ * A_ * 4;            // 2 MB
    float* w_read    = (float*)wsp;    wsp += (size_t)B_ * R_ * A_ * 4;       // 8 MB
    float* w_write   = (float*)wsp;    wsp += (size_t)B_ * A_ * 4;            // 2 MB
    // rv_part [2][B][RS] f32 = 1 MB: aliases xin_bf (dead after z-GEMM)
    float* rv_part   = (float*)xin_bf;

    // 1. setup: all weight transposes (bf16) + xin prep in one dispatch
    setup_kernel<<<dim3(4096 + 4096 + 928 + 512 + 256 + 2048), 256, 0, stream>>>(
        x, read_vec_prev, h_prev, Wx, Wh, Wint, Wo_h, Wout,
        xin_bf, WxhT, WpT, WoutT);
    // 2. z partials = xin @ [Wx;Wh]  (split-K=4: grid 1024 blocks = 4/CU)
    gemm_bf16_k<true><<<dim3(4096 / 64, B_ / 64, SK_), 256, 0, stream>>>(
        xin_bf, 2048, WxhT, 2048, zpart, 4096, 2048 / SK_);
    // 3. gates -> h (bf16); sums z partials + b_lstm
    gates_kernel<<<dim3(B_ * H_ / 1024), 256, 0, stream>>>(zpart, b_lstm, c_prev, h_bf);
    // 4. poh partials = h @ [Wint|Wo_h]  (N=1438, split-K=4: 368 blocks)
    gemm_bf16_k<false><<<dim3(23, B_ / 64, SK_), 256, 0, stream>>>(
        h_bf, 1024, WpT, 1024, pohpart, NP_, 1024 / SK_);
    // 5. dots + norms (first pass over memory, f32x4)
    sim_kernel<<<dim3(A_ / 1024, B_), 256, 0, stream>>>(memory_prev, pohpart, b_int, dots, mn);
    // 6. addressing for 4 read heads + 1 write head
    address_kernel<<<dim3(5, B_), 256, 0, stream>>>(
        pohpart, b_int, dots, mn, read_w_prev, write_w_prev, w_read, w_write);
    // 7. memory update + read vectors (second pass over memory, w reg-cached)
    update_kernel<<<dim3(B_ * 32), 256, 0, stream>>>(
        memory_prev, pohpart, b_int, w_read, w_write, mem_new_out, rv_part);
    // 8. final_output = (oh partials + bo_h) + rv @ Wout + b_out
    gemm_final_k<<<dim3(O_ / 64, B_ / 64), 256, 0, stream>>>(
        rv_part, WoutT, pohpart, bo_h, b_out, out);
}

// Round 3
// 614.555 us; speedup vs baseline: 1.1966x; 1.0338x over previous
//
#include <hip/hip_runtime.h>
#include <math.h>

// Problem constants
#define B_ 256
#define I_ 512
#define H_ 1024
#define M_ 128
#define A_ 2048
#define R_ 4
#define S_ 3
#define O_ 512
#define RS_ 512      // R*M
#define P_ 926       // R*(M+S+3) + 3*M+S+3
#define PW_OFF 536   // R*(M+S+3)
#define NP_ 1438     // 926 (Wint) ++ 512 (Wo_h) concatenated N
#define SK_ 4        // split-K factor for the two big GEMMs

typedef unsigned short ushort_t;
typedef __attribute__((ext_vector_type(8))) short bf16x8;
typedef __attribute__((ext_vector_type(4))) float f32x4;
typedef __attribute__((ext_vector_type(4))) unsigned short u16x4;

__device__ __forceinline__ float sigmoidf_(float x) { return 1.0f / (1.0f + expf(-x)); }
__device__ __forceinline__ float softplusf_(float x) {
    return (x > 20.0f) ? x : log1pf(expf(x));
}
// f32 -> bf16 round-to-nearest-even
__device__ __forceinline__ ushort_t f2bf(float f) {
    unsigned int u = __float_as_uint(f);
    u = (u + 0x7FFFu + ((u >> 16) & 1u)) >> 16;
    return (ushort_t)u;
}

// sum of SK_ split-K partials of the p/oh GEMM (+ b_int bias), col < 926
__device__ __forceinline__ float pval(const float* __restrict__ pp,
                                      const float* __restrict__ b_int,
                                      int b, int col) {
    size_t o = (size_t)b * NP_ + col;
    size_t st = (size_t)B_ * NP_;
    return b_int[col] + pp[o] + pp[o + st] + pp[o + 2 * st] + pp[o + 3 * st];
}

// ---------------- block reductions (512 threads = 8 waves) ----------------
// Leading __syncthreads protects red[] from the previous reduction's reads.
__device__ __forceinline__ float bsum8(float v, float* red, int wv, int l) {
    #pragma unroll
    for (int off = 32; off; off >>= 1) v += __shfl_down(v, off, 64);
    __syncthreads();
    if (l == 0) red[wv] = v;
    __syncthreads();
    return red[0] + red[1] + red[2] + red[3] + red[4] + red[5] + red[6] + red[7];
}
__device__ __forceinline__ float bmax8(float v, float* red, int wv, int l) {
    #pragma unroll
    for (int off = 32; off; off >>= 1) v = fmaxf(v, __shfl_down(v, off, 64));
    __syncthreads();
    if (l == 0) red[wv] = v;
    __syncthreads();
    float m0 = fmaxf(fmaxf(red[0], red[1]), fmaxf(red[2], red[3]));
    float m1 = fmaxf(fmaxf(red[4], red[5]), fmaxf(red[6], red[7]));
    return fmaxf(m0, m1);
}

// ---------------- fused setup: 4 weight transposes + input prep ------------
// transpose+convert one 32x32 tile: WT[n][koff+k] = bf16(W[k][n])
__device__ __forceinline__ void transpose_tile(
    const float* __restrict__ W, ushort_t* __restrict__ WT,
    int K, int N, int ostride, int koff, int bx, int by, float (*tile)[33])
{
    int k0 = by * 32, n0 = bx * 32;
    int tx = threadIdx.x & 31, ty = threadIdx.x >> 5;  // ty 0..7
    #pragma unroll
    for (int i = 0; i < 4; ++i) {
        int k = ty + i * 8;
        int n = n0 + tx;
        float v = (n < N) ? W[(size_t)(k0 + k) * N + n] : 0.0f;
        tile[tx][k] = v;   // tile[n_local][k_local]
    }
    __syncthreads();
    #pragma unroll
    for (int i = 0; i < 4; ++i) {
        int nl = ty + i * 8;
        int n = n0 + nl;
        if (n < N) WT[(size_t)n * ostride + koff + k0 + tx] = f2bf(tile[nl][tx]);
    }
}

// region sizes: Wx 4096 | Wh 4096 | Wint 928 | Wo_h 512 | prep 2048
__global__ __launch_bounds__(256) void setup_kernel(
    const float* __restrict__ x, const float* __restrict__ rv,
    const float* __restrict__ hp,
    const float* __restrict__ Wx, const float* __restrict__ Wh,
    const float* __restrict__ Wint, const float* __restrict__ Wo_h,
    ushort_t* __restrict__ xin, ushort_t* __restrict__ WxhT,
    ushort_t* __restrict__ WpT)
{
    __shared__ float tile[32][33];
    int r = blockIdx.x;
    if (r < 4096) { transpose_tile(Wx, WxhT, 1024, 4096, 2048, 0,    r % 128, r / 128, tile); return; }
    r -= 4096;
    if (r < 4096) { transpose_tile(Wh, WxhT, 1024, 4096, 2048, 1024, r % 128, r / 128, tile); return; }
    r -= 4096;
    if (r < 928)  { transpose_tile(Wint, WpT, 1024, 926, 1024, 0,    r % 29,  r / 29,  tile); return; }
    r -= 928;
    if (r < 512)  { transpose_tile(Wo_h, WpT + (size_t)926 * 1024, 1024, 512, 1024, 0, r % 16, r / 16, tile); return; }
    r -= 512;
    // prep: xin_bf = bf16([x | read_vec_prev | h_prev]); r in [0, 2048)
    int idx = r * 256 + threadIdx.x;   // B*2048
    int b = idx >> 11, j = idx & 2047;
    float v;
    if (j < 512)       v = x[b * 512 + j];
    else if (j < 1024) v = rv[b * 512 + (j - 512)];
    else               v = hp[b * 1024 + (j - 1024)];
    xin[idx] = f2bf(v);
}

// ---------------- bf16 MFMA GEMM, split-K partial output -------------------
// A: [M][lda] bf16; BT: [N][ldb] bf16 (W^T). blockIdx.z = split-K slice kz;
// each slice covers K range [kz*Ks, (kz+1)*Ks) and writes its own partial
// Cpart[kz][M][N] (f32, no bias). Consumers sum the SK_ partials.
template<bool NALIGN>
__global__ __launch_bounds__(256) void gemm_bf16_k(
    const ushort_t* __restrict__ A, int lda,
    const ushort_t* __restrict__ BT, int ldb,
    float* __restrict__ Cpart,
    int N, int Ks)
{
    __shared__ ushort_t As[64][40];   // pad 32->40 (80B rows: 2-way bank alias = free)
    __shared__ ushort_t Bs[64][40];
    int tid = threadIdx.x;
    int bm0 = blockIdx.y * 64, bn0 = blockIdx.x * 64;
    int kbeg = blockIdx.z * Ks, kend = kbeg + Ks;
    int srow = tid >> 2;              // staging: 64 rows x 4 threads x 8 elems
    int scol = (tid & 3) << 3;
    int wv = tid >> 6, l = tid & 63;
    int wm = (wv & 1) * 32, wn = (wv >> 1) * 32;
    int lane16 = l & 15, quad = l >> 4;

    f32x4 z4 = {0.0f, 0.0f, 0.0f, 0.0f};
    f32x4 acc00 = z4, acc01 = z4, acc10 = z4, acc11 = z4;

    const ushort_t* ap = A + (size_t)(bm0 + srow) * lda + scol;
    bool bvalid = NALIGN || (bn0 + srow) < N;
    const ushort_t* bp = BT + (size_t)(bn0 + srow) * ldb + scol;
    float4 fz = {0.0f, 0.0f, 0.0f, 0.0f};

    for (int k0 = kbeg; k0 < kend; k0 += 32) {
        *(float4*)&As[srow][scol] = *(const float4*)(ap + k0);
        if (bvalid) *(float4*)&Bs[srow][scol] = *(const float4*)(bp + k0);
        else        *(float4*)&Bs[srow][scol] = fz;
        __syncthreads();
        bf16x8 a0 = *(const bf16x8*)&As[wm + lane16][quad * 8];
        bf16x8 a1 = *(const bf16x8*)&As[wm + 16 + lane16][quad * 8];
        bf16x8 b0 = *(const bf16x8*)&Bs[wn + lane16][quad * 8];
        bf16x8 b1 = *(const bf16x8*)&Bs[wn + 16 + lane16][quad * 8];
        acc00 = __builtin_amdgcn_mfma_f32_16x16x32_bf16(a0, b0, acc00, 0, 0, 0);
        acc01 = __builtin_amdgcn_mfma_f32_16x16x32_bf16(a0, b1, acc01, 0, 0, 0);
        acc10 = __builtin_amdgcn_mfma_f32_16x16x32_bf16(a1, b0, acc10, 0, 0, 0);
        acc11 = __builtin_amdgcn_mfma_f32_16x16x32_bf16(a1, b1, acc11, 0, 0, 0);
        __syncthreads();
    }

    float* C = Cpart + (size_t)blockIdx.z * gridDim.y * 64 * N;
    // D layout: col = lane&15, row = quad*4 + reg
    #pragma unroll
    for (int gi = 0; gi < 2; ++gi) {
        #pragma unroll
        for (int gj = 0; gj < 2; ++gj) {
            const f32x4& acc = gi == 0 ? (gj == 0 ? acc00 : acc01)
                                       : (gj == 0 ? acc10 : acc11);
            int col = bn0 + wn + gj * 16 + lane16;
            if (NALIGN || col < N) {
                #pragma unroll
                for (int r2 = 0; r2 < 4; ++r2) {
                    int row = bm0 + wm + gi * 16 + quad * 4 + r2;
                    C[(size_t)row * N + col] = acc[r2];
                }
            }
        }
    }
}

// ---------------- LSTM gates (float4, sums 4 z-partials + bias) ------------
__global__ __launch_bounds__(256) void gates_kernel(
    const float* __restrict__ zpart, const float* __restrict__ b_lstm,
    const float* __restrict__ c_prev, ushort_t* __restrict__ h)
{
    int g = blockIdx.x * 256 + threadIdx.x;   // B*H/4 = 65536
    int b = g >> 8, j = (g & 255) << 2;
    size_t st = (size_t)B_ * 4096;
    size_t zb = (size_t)b * 4096 + j;
    f32x4 zs[4];
    #pragma unroll
    for (int q = 0; q < 4; ++q) {
        size_t o = zb + q * 1024;
        f32x4 v = *(const f32x4*)(zpart + o);
        v += *(const f32x4*)(zpart + o + st);
        v += *(const f32x4*)(zpart + o + 2 * st);
        v += *(const f32x4*)(zpart + o + 3 * st);
        v += *(const f32x4*)(b_lstm + q * 1024 + j);
        zs[q] = v;
    }
    f32x4 cp = *(const f32x4*)(c_prev + (size_t)b * 1024 + j);
    u16x4 hv;
    #pragma unroll
    for (int e = 0; e < 4; ++e) {
        float c = sigmoidf_(zs[1][e]) * cp[e] + sigmoidf_(zs[0][e]) * tanhf(zs[2][e]);
        hv[e] = f2bf(sigmoidf_(zs[3][e]) * tanhf(c));
    }
    *(u16x4*)(h + (size_t)b * 1024 + j) = hv;
}

// ---------------- mega kernel: sim + addressing + update + final output ----
// One block per batch b (grid 256, 512 threads, ~67 KB LDS, 1 block/CU).
// All intermediates (dots, mn, w's, rv) live in LDS; memory_prev is streamed
// twice with a short reuse distance (partial L3 hits on the second pass).
__global__ __launch_bounds__(512) void mega_kernel(
    const float* __restrict__ mem, const float* __restrict__ pohpart,
    const float* __restrict__ b_int,
    const float* __restrict__ read_w_prev, const float* __restrict__ write_w_prev,
    const float* __restrict__ Wout, const float* __restrict__ bo_h,
    const float* __restrict__ b_out,
    float* __restrict__ out,        // [B][O]
    float* __restrict__ mem_new)    // [B][M][A]
{
    int b = blockIdx.x;
    int t = threadIdx.x;            // 0..511
    int wv = t >> 6, l = t & 63;    // 8 waves

    __shared__ float dw[5][A_];         // dots -> (overwritten) head weights, 40 KB
    __shared__ float wg[A_];            // gated-weight scratch / rv buffer, 8 KB
    __shared__ float ks[5][M_];         // keys; reused as er/ad in phase 4, 2.5 KB
    __shared__ float rvp[M_][8][4];     // rv wave partials; reused as out partials, 16 KB
    __shared__ float red[8];

    // ---- phase 1: keys into LDS ----
    for (int idx = t; idx < 5 * M_; idx += 512) {
        int h = idx >> 7, m = idx & 127;
        int col = (h < 4) ? h * 134 + m : PW_OFF + m;
        ks[h][m] = pval(pohpart, b_int, b, col);
    }
    __syncthreads();

    // ---- phase 2: dots (5 heads) + column norms; thread owns cols 4t..4t+3 -
    const float* mb = mem + (size_t)b * M_ * A_ + 4 * t;
    f32x4 z = {0.0f, 0.0f, 0.0f, 0.0f};
    f32x4 d0 = z, d1 = z, d2 = z, d3 = z, d4 = z, nn = z;
    #pragma unroll 2
    for (int m = 0; m < M_; m += 4) {
        f32x4 vv[4];
        #pragma unroll
        for (int mm = 0; mm < 4; ++mm)
            vv[mm] = *(const f32x4*)(mb + (size_t)(m + mm) * A_);
        #pragma unroll
        for (int mm = 0; mm < 4; ++mm) {
            float k0 = ks[0][m + mm], k1 = ks[1][m + mm], k2 = ks[2][m + mm];
            float k3 = ks[3][m + mm], k4 = ks[4][m + mm];
            #pragma unroll
            for (int c = 0; c < 4; ++c) {
                float v = vv[mm][c];
                d0[c] += v * k0; d1[c] += v * k1; d2[c] += v * k2;
                d3[c] += v * k3; d4[c] += v * k4;
                nn[c] += v * v;
            }
        }
    }
    *(f32x4*)&dw[0][4 * t] = d0;
    *(f32x4*)&dw[1][4 * t] = d1;
    *(f32x4*)&dw[2][4 * t] = d2;
    *(f32x4*)&dw[3][4 * t] = d3;
    *(f32x4*)&dw[4][4 * t] = d4;
    f32x4 rt;
    #pragma unroll
    for (int c = 0; c < 4; ++c) rt[c] = sqrtf(nn[c]);  // stays in registers

    // ---- phase 3: addressing per head (dots consumed, w written in place) --
    for (int head = 0; head < 5; ++head) {
        int pb = (head < 4) ? head * 134 : PW_OFF;
        float beta  = softplusf_(pval(pohpart, b_int, b, pb + 128));
        float g     = sigmoidf_(pval(pohpart, b_int, b, pb + 129));
        float gamma = 1.0f + softplusf_(pval(pohpart, b_int, b, pb + 130));
        float e0 = pval(pohpart, b_int, b, pb + 131);
        float e1 = pval(pohpart, b_int, b, pb + 132);
        float e2 = pval(pohpart, b_int, b, pb + 133);
        float smax = fmaxf(e0, fmaxf(e1, e2));
        float x0 = __expf(e0 - smax), x1 = __expf(e1 - smax), x2 = __expf(e2 - smax);
        float sden = x0 + x1 + x2;
        float s0 = x0 / sden, s1 = x1 / sden, s2 = x2 / sden;

        float kacc = (t < M_) ? ks[head][t] * ks[head][t] : 0.0f;
        float kn = sqrtf(bsum8(kacc, red, wv, l));

        f32x4 dd = *(const f32x4*)&dw[head][4 * t];   // own cols (self-written)
        f32x4 lg;
        float lmax = -1e30f;
        #pragma unroll
        for (int c = 0; c < 4; ++c) {
            lg[c] = beta * dd[c] / (kn * rt[c] + 1e-8f);
            lmax = fmaxf(lmax, lg[c]);
        }
        lmax = bmax8(lmax, red, wv, l);
        f32x4 ex;
        float lsum = 0.0f;
        #pragma unroll
        for (int c = 0; c < 4; ++c) { ex[c] = __expf(lg[c] - lmax); lsum += ex[c]; }
        lsum = bsum8(lsum, red, wv, l);
        float inv_lsum = 1.0f / lsum;

        const float* wprev = (head < 4) ? read_w_prev + ((size_t)b * 4 + head) * A_
                                        : write_w_prev + (size_t)b * A_;
        f32x4 pv = *(const f32x4*)(wprev + 4 * t);
        f32x4 gv;
        #pragma unroll
        for (int c = 0; c < 4; ++c)
            gv[c] = g * (ex[c] * inv_lsum) + (1.0f - g) * pv[c];
        *(f32x4*)&wg[4 * t] = gv;
        __syncthreads();
        f32x4 wp;
        float psum = 0.0f;
        #pragma unroll
        for (int c = 0; c < 4; ++c) {
            int a = 4 * t + c;
            float ws = s0 * wg[(a + 1) & (A_ - 1)] + s1 * wg[a] + s2 * wg[(a + A_ - 1) & (A_ - 1)];
            wp[c] = __expf(gamma * __logf(ws + 1e-12f));   // (ws+eps)^gamma
            psum += wp[c];
        }
        psum = bsum8(psum, red, wv, l);
        float inv = 1.0f / (psum + 1e-8f);
        #pragma unroll
        for (int c = 0; c < 4; ++c) wp[c] *= inv;
        *(f32x4*)&dw[head][4 * t] = wp;      // w overwrites this head's dots
        __syncthreads();                      // wg reused next head
    }

    // ---- phase 4: memory update + rv wave-partials ----
    float* er_s = &ks[0][0];                 // ks is dead; reuse for erase/add
    float* ad_s = &ks[1][0];
    if (t < M_)            er_s[t] = sigmoidf_(pval(pohpart, b_int, b, 670 + t));
    else if (t < 2 * M_)   ad_s[t - M_] = pval(pohpart, b_int, b, 798 + (t - M_));
    __syncthreads();

    f32x4 ww = *(const f32x4*)&dw[4][4 * t];
    f32x4 w0 = *(const f32x4*)&dw[0][4 * t];
    f32x4 w1 = *(const f32x4*)&dw[1][4 * t];
    f32x4 w2 = *(const f32x4*)&dw[2][4 * t];
    f32x4 w3 = *(const f32x4*)&dw[3][4 * t];
    const float* mrow = mem + (size_t)b * M_ * A_ + 4 * t;
    float* orow = mem_new + (size_t)b * M_ * A_ + 4 * t;
    #pragma unroll 1
    for (int m0v = 0; m0v < M_; m0v += 4) {
        f32x4 vv[4];
        #pragma unroll
        for (int mm = 0; mm < 4; ++mm)
            vv[mm] = *(const f32x4*)(mrow + (size_t)(m0v + mm) * A_);
        #pragma unroll
        for (int mm = 0; mm < 4; ++mm) {
            float er = er_s[m0v + mm], ad = ad_s[m0v + mm];
            f32x4 ov;
            float a0 = 0, a1 = 0, a2 = 0, a3 = 0;
            #pragma unroll
            for (int c = 0; c < 4; ++c) {
                float v = vv[mm][c];
                ov[c] = v * (1.0f - er * ww[c]) + ad * ww[c];
                a0 += v * w0[c]; a1 += v * w1[c]; a2 += v * w2[c]; a3 += v * w3[c];
            }
            *(f32x4*)(orow + (size_t)(m0v + mm) * A_) = ov;
            float ah0 = a0, ah1 = a1, ah2 = a2, ah3 = a3;
            #pragma unroll
            for (int off = 32; off; off >>= 1) {
                ah0 += __shfl_down(ah0, off, 64);
                ah1 += __shfl_down(ah1, off, 64);
                ah2 += __shfl_down(ah2, off, 64);
                ah3 += __shfl_down(ah3, off, 64);
            }
            if (l == 0) {
                rvp[m0v + mm][wv][0] = ah0;
                rvp[m0v + mm][wv][1] = ah1;
                rvp[m0v + mm][wv][2] = ah2;
                rvp[m0v + mm][wv][3] = ah3;
            }
        }
    }
    __syncthreads();

    // rv finalize into wg space: rv[k], k = head*128 + m = t
    float* rvs = wg;
    {
        int h = t >> 7, m = t & 127;
        float s = 0.0f;
        #pragma unroll
        for (int w8 = 0; w8 < 8; ++w8) s += rvp[m][w8][h];
        rvs[t] = s;
    }
    __syncthreads();

    // ---- phase 5: final_output row = oh + bo_h + b_out + rv @ Wout --------
    // quarter q of K owned by t>>7; 4 consecutive outputs per thread.
    float* part = &rvp[0][0][0];             // reuse rvp as [4][512] partials
    {
        int q = t >> 7;
        int oc = (t & 127) * 4;
        f32x4 acc = {0.0f, 0.0f, 0.0f, 0.0f};
        const float* wob = Wout + (size_t)q * M_ * O_ + oc;
        #pragma unroll 4
        for (int k = 0; k < M_; ++k) {
            float rvk = rvs[q * M_ + k];
            f32x4 wv4 = *(const f32x4*)(wob + (size_t)k * O_);
            #pragma unroll
            for (int c = 0; c < 4; ++c) acc[c] += rvk * wv4[c];
        }
        *(f32x4*)&part[q * 512 + oc] = acc;
    }
    __syncthreads();
    {
        int o = t;   // 512 outputs
        size_t st = (size_t)B_ * NP_;
        size_t po = (size_t)b * NP_ + 926 + o;
        float oh = pohpart[po] + pohpart[po + st] + pohpart[po + 2 * st] + pohpart[po + 3 * st];
        float s = part[o] + part[512 + o] + part[1024 + o] + part[1536 + o];
        out[(size_t)b * O_ + o] = s + oh + bo_h[o] + b_out[o];
    }
}

extern "C" void kernel_launch(void* const* d_in, const int* in_sizes, int n_in,
                              void* d_out, int out_size, void* d_ws, size_t ws_size,
                              hipStream_t stream) {
    (void)in_sizes; (void)n_in; (void)out_size; (void)ws_size;
    const float* x            = (const float*)d_in[0];
    const float* h_prev       = (const float*)d_in[1];
    const float* c_prev       = (const float*)d_in[2];
    const float* read_w_prev  = (const float*)d_in[3];
    const float* write_w_prev = (const float*)d_in[4];
    const float* memory_prev  = (const float*)d_in[5];
    const float* read_vec_prev= (const float*)d_in[6];
    const float* Wx           = (const float*)d_in[7];
    const float* Wh           = (const float*)d_in[8];
    const float* b_lstm       = (const float*)d_in[9];
    const float* Wo_h         = (const float*)d_in[10];
    const float* bo_h         = (const float*)d_in[11];
    const float* Wint         = (const float*)d_in[12];
    const float* b_int        = (const float*)d_in[13];
    const float* Wout         = (const float*)d_in[14];
    const float* b_out        = (const float*)d_in[15];
    float* out = (float*)d_out;                  // [B*O] ++ [B*M*A]
    float* mem_new_out = out + (size_t)B_ * O_;

    char* wsp = (char*)d_ws;
    ushort_t* xin_bf = (ushort_t*)wsp; wsp += (size_t)B_ * 2048 * 2;          // 1 MB
    ushort_t* h_bf   = (ushort_t*)wsp; wsp += (size_t)B_ * H_ * 2;            // 0.5 MB
    ushort_t* WxhT   = (ushort_t*)wsp; wsp += (size_t)4096 * 2048 * 2;        // 16 MB
    ushort_t* WpT    = (ushort_t*)wsp; wsp += (size_t)NP_ * 1024 * 2;         // 2.94 MB
    float* zpart     = (float*)wsp;    wsp += (size_t)SK_ * B_ * 4096 * 4;    // 16 MB
    float* pohpart   = (float*)wsp;    wsp += (size_t)SK_ * B_ * NP_ * 4;     // 5.9 MB

    // 1. setup: weight transposes (bf16) + xin prep in one dispatch
    setup_kernel<<<dim3(4096 + 4096 + 928 + 512 + 2048), 256, 0, stream>>>(
        x, read_vec_prev, h_prev, Wx, Wh, Wint, Wo_h,
        xin_bf, WxhT, WpT);
    // 2. z partials = xin @ [Wx;Wh]  (split-K=4: grid 1024 blocks = 4/CU)
    gemm_bf16_k<true><<<dim3(4096 / 64, B_ / 64, SK_), 256, 0, stream>>>(
        xin_bf, 2048, WxhT, 2048, zpart, 4096, 2048 / SK_);
    // 3. gates -> h (bf16); sums z partials + b_lstm
    gates_kernel<<<dim3(B_ * H_ / 1024), 256, 0, stream>>>(zpart, b_lstm, c_prev, h_bf);
    // 4. poh partials = h @ [Wint|Wo_h]  (N=1438, split-K=4: 368 blocks)
    gemm_bf16_k<false><<<dim3(23, B_ / 64, SK_), 256, 0, stream>>>(
        h_bf, 1024, WpT, 1024, pohpart, NP_, 1024 / SK_);
    // 5. mega: sim + addressing + update + read-vec + final output
    mega_kernel<<<dim3(B_), 512, 0, stream>>>(
        memory_prev, pohpart, b_int, read_w_prev, write_w_prev,
        Wout, bo_h, b_out, out, mem_new_out);
}